// Round 10
// baseline (1187.291 us; speedup 1.0000x reference)
//
#include <hip/hip_runtime.h>
#include <cstdint>

// Problem constants (B=8, C=80, H=W=128, K=100, kernel=3, num_dets=1000)
#define NB    8
#define NC    80
#define HH    128
#define WW    128
#define HW    16384
#define CHW   1310720
#define KTOP  100
#define NDET  1000
#define NPAIR 10000
#define CAP   4096
#define ACAP  2048
#define NBINS 4096
#define BLK_SURV 1024     // per-block survivor segment (expect ~900)
#define NSEG  160         // k_nms blocks per (tensor,batch)

// ---- workspace layout (bytes) ----
#define OFF_CCNT   0                         // int[24*32] (one counter per 128B)
#define OFF_OVF    3072                      // int[32]
#define OFF_HIST   3200                      // u32[24][4096]
#define ZERO_BYTES 396416                    // ccnt+ovf+hist
#define OFF_THR    396416                    // int[32]
#define OFF_BLKCNT 396544                    // int[24*160]
#define OFF_CAND   411904                    // u64[24][4096]
#define OFF_CS     1198336                   // float[2400]
#define OFF_CX     1207936
#define OFF_CY     1217536
#define OFF_CE     1227136
#define OFF_CCLS   1236736                   // int[2400]
#define OFF_SURV   1246336                   // u64[24][160][1024] = 31.5 MB
#define WS_NEEDED  (OFF_SURV + 24*NSEG*BLK_SURV*8)

// branchless, bit-identical to jax.nn.sigmoid's two-branch form
__device__ __forceinline__ float sigmoidf(float x) {
    float e = expf(-fabsf(x));
    return (x >= 0.f ? 1.f : e) / (1.f + e);
}

// ---- kernel 1: NMS + compacted survivor segments + direct global hist ----
// Minimal serial structure: 2 barriers, 8.2 KB LDS, no LDS histogram.
// Per-survivor hist update is a fire-and-forget global atomic (drains at endpgm).
__global__ void __launch_bounds__(256, 6) k_nms(
        const float* __restrict__ tl, const float* __restrict__ br,
        const float* __restrict__ ct,
        uint64_t* __restrict__ surv, int* __restrict__ blkcnt,
        int* __restrict__ ovf, uint32_t* __restrict__ hist) {
    __shared__ uint2 lsurv[BLK_SURV];    // 8 KB
    __shared__ int   woff[4];

    int tid = threadIdx.x;
    int bc = blockIdx.y; int t = bc >> 3; int b = bc & 7;
    const float* heat = (t == 0) ? tl : (t == 1) ? br : ct;
    int seg = blockIdx.x;
    int chan = seg >> 1;
    int half = seg & 1;
    const float* cb = heat + (size_t)b * CHW + (size_t)chan * HW;
    int lane = tid & 63;
    int wid = tid >> 6;
    int band = (wid << 1) + (lane >> 5);             // 0..7
    int ybase = half * 64 + band * 8;                // 0..120
    int x0 = (lane & 31) << 2;
    const float NEG = -__builtin_inff();

    // phase A: 10 unconditional loads (clamped row), pinned live
    float4 L[10];
    #pragma unroll
    for (int r = 0; r < 10; ++r) {
        int yy = ybase - 1 + r;
        int yc = min(max(yy, 0), HH - 1);
        L[r] = *(const float4*)(cb + yc * WW + x0);
    }
    #pragma unroll
    for (int r = 0; r < 10; ++r)
        asm volatile("" : "+v"(L[r].x), "+v"(L[r].y), "+v"(L[r].z), "+v"(L[r].w));
    if (ybase == 0)       L[0] = make_float4(NEG, NEG, NEG, NEG);
    if (ybase == HH - 8)  L[9] = make_float4(NEG, NEG, NEG, NEG);

    uint32_t mask = 0;
    #pragma unroll
    for (int j = 0; j < 8; ++j) {
        float c0 = fmaxf(fmaxf(L[j].x, L[j+1].x), L[j+2].x);
        float c1 = fmaxf(fmaxf(L[j].y, L[j+1].y), L[j+2].y);
        float c2 = fmaxf(fmaxf(L[j].z, L[j+1].z), L[j+2].z);
        float c3 = fmaxf(fmaxf(L[j].w, L[j+1].w), L[j+2].w);
        float cl = __shfl_up(c3, 1);
        float cr = __shfl_down(c0, 1);
        if (x0 == 0)      cl = NEG;
        if (x0 == WW - 4) cr = NEG;
        if (fmaxf(fmaxf(cl, c0), c1) == L[j+1].x) mask |= 1u << (j*4+0);
        if (fmaxf(fmaxf(c0, c1), c2) == L[j+1].y) mask |= 1u << (j*4+1);
        if (fmaxf(fmaxf(c1, c2), c3) == L[j+1].z) mask |= 1u << (j*4+2);
        if (fmaxf(fmaxf(c2, c3), cr) == L[j+1].w) mask |= 1u << (j*4+3);
    }

    // phase B: block-wide compaction into LDS (no global traffic)
    int cnt = __popc(mask);
    int incl = cnt;
    #pragma unroll
    for (int d = 1; d < 64; d <<= 1) {
        int u = __shfl_up(incl, d);
        if (lane >= d) incl += u;
    }
    if (lane == 63) woff[wid] = incl;
    __syncthreads();
    int pre = 0, total = 0;
    #pragma unroll
    for (int w = 0; w < 4; ++w) {
        int tw = woff[w];
        if (w < wid) pre += tw;
        total += tw;
    }
    int base = pre + incl - cnt;
    if (mask) {
        int ib = chan * HW + ybase * WW + x0;
        #pragma unroll
        for (int j = 0; j < 8; ++j) {
            #pragma unroll
            for (int p = 0; p < 4; ++p) {
                if (mask & (1u << (j * 4 + p))) {
                    float v = (p == 0) ? L[j+1].x : (p == 1) ? L[j+1].y
                            : (p == 2) ? L[j+1].z : L[j+1].w;
                    if (base < BLK_SURV)
                        lsurv[base] = make_uint2(__float_as_uint(v),
                                                 (uint32_t)(ib + j * WW + p));
                    ++base;
                }
            }
        }
    }
    __syncthreads();

    // phase C: dense sigmoid + coalesced segment store + global hist atomics
    if (tid == 0) {
        blkcnt[bc * NSEG + seg] = min(total, BLK_SURV);
        if (total > BLK_SURV) ovf[bc] = 1;
    }
    int tt = min(total, BLK_SURV);
    uint64_t* sv = surv + ((size_t)bc * NSEG + seg) * BLK_SURV;
    uint32_t* gh = hist + (size_t)bc * NBINS;
    for (int i = tid; i < tt; i += 256) {
        uint2 e = lsurv[i];
        uint32_t bt = __float_as_uint(sigmoidf(__uint_as_float(e.x)));
        sv[i] = ((uint64_t)bt << 32) | (uint32_t)(~e.y);
        atomicAdd(&gh[bt >> 19], 1u);   // fire-and-forget, low contention
    }
}

// on-the-fly key for the (never-expected) survivor-overflow fallback
__device__ uint64_t key_at(const float* __restrict__ hb, int i) {
    float v = hb[i];
    int rem = i & (HW - 1);
    int y = rem >> 7, x = rem & (WW - 1);
    bool mx = true;
    if (y > 0) {
        if (x > 0      && hb[i - WW - 1] > v) mx = false;
        if (              hb[i - WW    ] > v) mx = false;
        if (x < WW - 1 && hb[i - WW + 1] > v) mx = false;
    }
    if (x > 0      && hb[i - 1] > v) mx = false;
    if (x < WW - 1 && hb[i + 1] > v) mx = false;
    if (y < HH - 1) {
        if (x > 0      && hb[i + WW - 1] > v) mx = false;
        if (              hb[i + WW    ] > v) mx = false;
        if (x < WW - 1 && hb[i + WW + 1] > v) mx = false;
    }
    if (!mx) return 0;
    return ((uint64_t)__float_as_uint(sigmoidf(v)) << 32) | (uint32_t)(~(uint32_t)i);
}

// ---- kernel 2: parallel threshold find (24 blocks) ----
__global__ void __launch_bounds__(256) k_thresh(const uint32_t* __restrict__ hist,
                                                int* __restrict__ thr) {
    __shared__ uint32_t csum[256];
    int bc = blockIdx.x;
    const uint32_t* h = hist + (size_t)bc * NBINS;
    int tid = threadIdx.x;
    uint32_t bins[16];
    #pragma unroll
    for (int i = 0; i < 16; ++i) bins[i] = h[tid * 16 + i];
    if (tid == 0) bins[0] = 0;  // bin 0 excluded
    uint32_t s = 0;
    #pragma unroll
    for (int i = 0; i < 16; ++i) s += bins[i];
    csum[tid] = s;
    __syncthreads();
    for (int step = 1; step < 256; step <<= 1) {
        uint32_t add = (tid + step < 256) ? csum[tid + step] : 0;
        __syncthreads();
        csum[tid] += add;
        __syncthreads();
    }
    uint32_t inc = csum[tid];
    uint32_t above = (tid + 1 < 256) ? csum[tid + 1] : 0;
    if (tid == 0 && inc < KTOP) thr[bc] = 1;
    if (above < KTOP && inc >= KTOP) {
        uint32_t cum = above;
        int T = 1;
        #pragma unroll
        for (int i = 15; i >= 0; --i) {
            cum += bins[i];
            if (cum >= KTOP) { T = tid * 16 + i; break; }
        }
        thr[bc] = T;
    }
}

// ---- kernel 3: wide filter of segmented survivors by bin >= T ----
__global__ void __launch_bounds__(256) k_filter(
        const uint64_t* __restrict__ surv, const int* __restrict__ blkcnt,
        const int* __restrict__ ovf, const int* __restrict__ thr,
        const float* __restrict__ tl, const float* __restrict__ br,
        const float* __restrict__ ct,
        uint64_t* __restrict__ cand, int* __restrict__ ccnt) {
    int bc = blockIdx.y;
    int T = thr[bc];
    if (!ovf[bc]) {
        const uint64_t* sv = surv + (size_t)bc * NSEG * BLK_SURV;
        const int* bcnt = blkcnt + bc * NSEG;
        for (int i = blockIdx.x * 256 + threadIdx.x; i < NSEG * BLK_SURV;
             i += 64 * 256) {
            int seg = i >> 10, pos = i & (BLK_SURV - 1);
            if (pos < bcnt[seg]) {
                uint64_t k = sv[i];
                if ((int)(uint32_t)(k >> 51) >= T) {
                    int pc = atomicAdd(&ccnt[bc * 32], 1);
                    if (pc < CAP) cand[(size_t)bc * CAP + pc] = k;
                }
            }
        }
    } else {
        int t = bc >> 3; int b = bc & 7;
        const float* heat = (t == 0) ? tl : (t == 1) ? br : ct;
        const float* hb = heat + (size_t)b * CHW;
        for (int i = blockIdx.x * 256 + threadIdx.x; i < CHW; i += 64 * 256) {
            uint64_t k = key_at(hb, i);
            if (k && (int)(uint32_t)(k >> 51) >= T) {
                int pc = atomicAdd(&ccnt[bc * 32], 1);
                if (pc < CAP) cand[(size_t)bc * CAP + pc] = k;
            }
        }
    }
}

// descending bitonic sort of N u64 keys in LDS
template <int N>
__device__ void bitonic_desc(uint64_t* k) {
    for (int kk = 2; kk <= N; kk <<= 1) {
        for (int j = kk >> 1; j > 0; j >>= 1) {
            __syncthreads();
            for (int i = threadIdx.x; i < N; i += blockDim.x) {
                int l = i ^ j;
                if (l > i) {
                    uint64_t a = k[i], b = k[l];
                    bool up = ((i & kk) == 0);
                    if (up ? (a < b) : (a > b)) { k[i] = b; k[l] = a; }
                }
            }
        }
    }
    __syncthreads();
}

// ---- kernel 4: per (tensor,batch) sort candidates, emit top-100 ----
__global__ void __launch_bounds__(1024) k_select(
        const uint64_t* __restrict__ cand, const int* __restrict__ ccnt,
        const float* __restrict__ tl_tag, const float* __restrict__ br_tag,
        const float* __restrict__ tl_regr, const float* __restrict__ br_regr,
        const float* __restrict__ ct_regr,
        float* __restrict__ cs, float* __restrict__ cx, float* __restrict__ cy,
        float* __restrict__ ce, int* __restrict__ ccls) {
    __shared__ uint64_t keys[CAP];
    int bc = blockIdx.x; int t = bc >> 3; int b = bc & 7;
    int n = ccnt[bc * 32]; if (n > CAP) n = CAP;
    if (n <= 512) {
        for (int i = threadIdx.x; i < 512; i += 1024)
            keys[i] = (i < n) ? cand[(size_t)bc * CAP + i] : 0ull;
        bitonic_desc<512>(keys);
    } else {
        for (int i = threadIdx.x; i < CAP; i += 1024)
            keys[i] = (i < n) ? cand[(size_t)bc * CAP + i] : 0ull;
        bitonic_desc<CAP>(keys);
    }
    if (threadIdx.x < KTOP) {
        uint64_t key = keys[threadIdx.x];
        float s = __uint_as_float((uint32_t)(key >> 32));
        uint32_t idx = ~(uint32_t)key;
        int cls = (int)(idx >> 14);
        int rem = (int)(idx & (HW - 1));
        int y = rem >> 7, x = rem & (WW - 1);
        const float* regr = (t == 0) ? tl_regr : (t == 1) ? br_regr : ct_regr;
        float o0 = regr[((size_t)b * 2 + 0) * HW + rem];
        float o1 = regr[((size_t)b * 2 + 1) * HW + rem];
        float emb = 0.f;
        if (t == 0) emb = tl_tag[(size_t)b * HW + rem];
        else if (t == 1) emb = br_tag[(size_t)b * HW + rem];
        int o = bc * KTOP + threadIdx.x;
        cs[o] = s;
        cx[o] = (float)x + o0;
        cy[o] = (float)y + o1;
        ce[o] = emb;
        ccls[o] = cls;
    }
}

// ---- kernel 5: fused pairwise scoring + final top-1000 + centers ----
__global__ void __launch_bounds__(1024) k_pairfinal(
        const float* __restrict__ cs, const float* __restrict__ cx,
        const float* __restrict__ cy, const float* __restrict__ ce,
        const int* __restrict__ ccls, float* __restrict__ out) {
    int b = blockIdx.x;
    __shared__ float ts[KTOP], tx[KTOP], ty[KTOP], te[KTOP];
    __shared__ int   tc[KTOP];
    __shared__ float bs_[KTOP], bx[KTOP], by[KTOP], be[KTOP];
    __shared__ int   bcl[KTOP];
    __shared__ uint64_t acc[ACAP];
    __shared__ int aidx[ACAP];
    __shared__ int acnt_s;
    int tid = threadIdx.x;
    if (tid == 0) acnt_s = 0;
    if (tid < KTOP) {
        int o = (0 * NB + b) * KTOP + tid;
        ts[tid] = cs[o]; tx[tid] = cx[o]; ty[tid] = cy[o]; te[tid] = ce[o]; tc[tid] = ccls[o];
    } else if (tid >= 512 && tid < 512 + KTOP) {
        int k = tid - 512;
        int o = (1 * NB + b) * KTOP + k;
        bs_[k] = cs[o]; bx[k] = cx[o]; by[k] = cy[o]; be[k] = ce[o]; bcl[k] = ccls[o];
    }
    __syncthreads();
    for (int p = tid; p < NPAIR; p += 1024) {
        int i = p / KTOP, j = p - i * KTOP;
        bool rej = (tc[i] != bcl[j])
                 | (fabsf(te[i] - be[j]) > 0.5f)
                 | (bx[j] < tx[i])
                 | (by[j] < ty[i]);
        if (!rej) {
            float sc = (ts[i] + bs_[j]) * 0.5f;
            int pos = atomicAdd(&acnt_s, 1);
            if (pos < ACAP)
                acc[pos] = ((uint64_t)__float_as_uint(sc) << 32) | (uint32_t)(~(uint32_t)p);
        }
    }
    __syncthreads();
    int m = acnt_s; if (m > ACAP) m = ACAP;
    if (m <= 256) {
        for (int i = tid; i < 256; i += 1024) if (i >= m) acc[i] = 0;
        bitonic_desc<256>(acc);
    } else {
        for (int i = tid; i < ACAP; i += 1024) if (i >= m) acc[i] = 0;
        bitonic_desc<ACAP>(acc);
    }
    for (int i = tid; i < m; i += 1024) aidx[i] = (int)(~(uint32_t)acc[i]);
    __syncthreads();
    for (int d = tid; d < NDET; d += 1024) {
        int p; float sc;
        if (d < m) {
            p = aidx[d];
            sc = __uint_as_float((uint32_t)(acc[d] >> 32));
        } else {
            // (d-m)-th flat pair-index NOT in accepted set, ascending (stable -1 ties)
            int r = d - m;
            int idx = r;
            for (;;) {
                int c = 0;
                for (int a = 0; a < m; ++a) c += (aidx[a] <= idx) ? 1 : 0;
                int ni = r + c;
                if (ni == idx) break;
                idx = ni;
            }
            p = idx; sc = -1.f;
        }
        int i = p / KTOP, j = p - i * KTOP;
        int ot = (0 * NB + b) * KTOP + i;
        int ob = (1 * NB + b) * KTOP + j;
        float* dr = out + ((size_t)b * NDET + d) * 8;
        dr[0] = cx[ot]; dr[1] = cy[ot]; dr[2] = cx[ob]; dr[3] = cy[ob];
        dr[4] = sc; dr[5] = cs[ot]; dr[6] = cs[ob]; dr[7] = (float)ccls[ot];
    }
    if (tid < KTOP) {
        int oc = (2 * NB + b) * KTOP + tid;
        float* cr = out + (size_t)NB * NDET * 8 + ((size_t)b * KTOP + tid) * 4;
        cr[0] = cx[oc]; cr[1] = cy[oc]; cr[2] = (float)ccls[oc]; cr[3] = cs[oc];
    }
}

extern "C" void kernel_launch(void* const* d_in, const int* in_sizes, int n_in,
                              void* d_out, int out_size, void* d_ws, size_t ws_size,
                              hipStream_t stream) {
    const float* tl_heat = (const float*)d_in[0];
    const float* br_heat = (const float*)d_in[1];
    const float* ct_heat = (const float*)d_in[2];
    const float* tl_tag  = (const float*)d_in[3];
    const float* br_tag  = (const float*)d_in[4];
    const float* tl_regr = (const float*)d_in[5];
    const float* br_regr = (const float*)d_in[6];
    const float* ct_regr = (const float*)d_in[7];

    if (ws_size < (size_t)WS_NEEDED) return;   // ~32.7 MB

    char* ws = (char*)d_ws;
    int*      ccnt   = (int*)(ws + OFF_CCNT);
    int*      ovf    = (int*)(ws + OFF_OVF);
    uint32_t* hist   = (uint32_t*)(ws + OFF_HIST);
    int*      thr    = (int*)(ws + OFF_THR);
    int*      blkcnt = (int*)(ws + OFF_BLKCNT);
    uint64_t* cand   = (uint64_t*)(ws + OFF_CAND);
    float*    cs     = (float*)(ws + OFF_CS);
    float*    cx     = (float*)(ws + OFF_CX);
    float*    cy     = (float*)(ws + OFF_CY);
    float*    ce     = (float*)(ws + OFF_CE);
    int*      ccls   = (int*)(ws + OFF_CCLS);
    uint64_t* surv   = (uint64_t*)(ws + OFF_SURV);

    hipMemsetAsync(ws, 0, ZERO_BYTES, stream);   // ccnt + ovf + hist

    k_nms<<<dim3(NSEG, 24), 256, 0, stream>>>(tl_heat, br_heat, ct_heat,
                                              surv, blkcnt, ovf, hist);
    k_thresh<<<24, 256, 0, stream>>>(hist, thr);
    k_filter<<<dim3(64, 24), 256, 0, stream>>>(surv, blkcnt, ovf, thr,
                                               tl_heat, br_heat, ct_heat,
                                               cand, ccnt);
    k_select<<<24, 1024, 0, stream>>>(cand, ccnt, tl_tag, br_tag,
                                      tl_regr, br_regr, ct_regr,
                                      cs, cx, cy, ce, ccls);
    k_pairfinal<<<NB, 1024, 0, stream>>>(cs, cx, cy, ce, ccls, (float*)d_out);
}

// Round 12
// 147.351 us; speedup vs baseline: 8.0576x; 8.0576x over previous
//
#include <hip/hip_runtime.h>
#include <cstdint>

// Problem constants (B=8, C=80, H=W=128, K=100, kernel=3, num_dets=1000)
#define NB    8
#define NC    80
#define HH    128
#define WW    128
#define HW    16384
#define CHW   1310720
#define KTOP  100
#define NDET  1000
#define NPAIR 10000
#define CAP   4096
#define ACAP  2048
#define NBINS 4096        // 12-bit bins over sigmoid bits (>>19) — proven resolution
#define BLK_SURV 1024     // per-block survivor segment (expect ~900)
#define NSEG  160         // k_nms blocks per (tensor,batch)

// ---- workspace layout (bytes) ----
#define OFF_CCNT   0                         // int[24*32] (one counter per 128B)
#define OFF_OVF    3072                      // int[32]
#define OFF_HIST   3200                      // u32[24][4096]
#define ZERO_BYTES 396416                    // ccnt+ovf+hist
#define OFF_THR    396416                    // int[32]
#define OFF_BLKCNT 396544                    // int[24*160]
#define OFF_CAND   411904                    // u64[24][4096]
#define OFF_CS     1198336                   // float[2400]
#define OFF_CX     1207936
#define OFF_CY     1217536
#define OFF_CE     1227136
#define OFF_CCLS   1236736                   // int[2400]
#define OFF_SURV   1246336                   // u64[24][160][1024] = 31.5 MB
#define WS_NEEDED  (OFF_SURV + 24*NSEG*BLK_SURV*8)

// branchless, bit-identical to jax.nn.sigmoid's two-branch form
__device__ __forceinline__ float sigmoidf(float x) {
    float e = expf(-fabsf(x));
    return (x >= 0.f ? 1.f : e) / (1.f + e);
}

// ---- kernel 1: NMS + compacted survivor segments (NO histogram work) ----
// Minimal structure: loads -> stencil -> scan -> scatter -> sigmoid+store.
// 8.2 KB LDS, 2 barriers, no global atomics on the critical path.
__global__ void __launch_bounds__(256, 8) k_nms(
        const float* __restrict__ tl, const float* __restrict__ br,
        const float* __restrict__ ct,
        uint64_t* __restrict__ surv, int* __restrict__ blkcnt,
        int* __restrict__ ovf) {
    __shared__ uint2 lsurv[BLK_SURV];    // 8 KB
    __shared__ int   woff[4];

    int tid = threadIdx.x;
    int bid = blockIdx.x;
    int bc = bid / NSEG;                 // bc-major: co-resident blocks share L2
    int seg = bid - bc * NSEG;
    int t = bc >> 3; int b = bc & 7;
    const float* heat = (t == 0) ? tl : (t == 1) ? br : ct;
    int chan = seg >> 1;
    int half = seg & 1;
    const float* cb = heat + (size_t)b * CHW + (size_t)chan * HW;
    int lane = tid & 63;
    int wid = tid >> 6;
    int band = (wid << 1) + (lane >> 5);             // 0..7
    int ybase = half * 64 + band * 8;                // 0..120
    int x0 = (lane & 31) << 2;
    const float NEG = -__builtin_inff();

    // phase A: 10 unconditional loads (clamped row), pinned live
    float4 L[10];
    #pragma unroll
    for (int r = 0; r < 10; ++r) {
        int yy = ybase - 1 + r;
        int yc = min(max(yy, 0), HH - 1);
        L[r] = *(const float4*)(cb + yc * WW + x0);
    }
    #pragma unroll
    for (int r = 0; r < 10; ++r)
        asm volatile("" : "+v"(L[r].x), "+v"(L[r].y), "+v"(L[r].z), "+v"(L[r].w));
    if (ybase == 0)       L[0] = make_float4(NEG, NEG, NEG, NEG);
    if (ybase == HH - 8)  L[9] = make_float4(NEG, NEG, NEG, NEG);

    uint32_t mask = 0;
    #pragma unroll
    for (int j = 0; j < 8; ++j) {
        float c0 = fmaxf(fmaxf(L[j].x, L[j+1].x), L[j+2].x);
        float c1 = fmaxf(fmaxf(L[j].y, L[j+1].y), L[j+2].y);
        float c2 = fmaxf(fmaxf(L[j].z, L[j+1].z), L[j+2].z);
        float c3 = fmaxf(fmaxf(L[j].w, L[j+1].w), L[j+2].w);
        float cl = __shfl_up(c3, 1);
        float cr = __shfl_down(c0, 1);
        if (x0 == 0)      cl = NEG;
        if (x0 == WW - 4) cr = NEG;
        if (fmaxf(fmaxf(cl, c0), c1) == L[j+1].x) mask |= 1u << (j*4+0);
        if (fmaxf(fmaxf(c0, c1), c2) == L[j+1].y) mask |= 1u << (j*4+1);
        if (fmaxf(fmaxf(c1, c2), c3) == L[j+1].z) mask |= 1u << (j*4+2);
        if (fmaxf(fmaxf(c2, c3), cr) == L[j+1].w) mask |= 1u << (j*4+3);
    }

    // phase B: block-wide compaction into LDS (no global traffic)
    int cnt = __popc(mask);
    int incl = cnt;
    #pragma unroll
    for (int d = 1; d < 64; d <<= 1) {
        int u = __shfl_up(incl, d);
        if (lane >= d) incl += u;
    }
    if (lane == 63) woff[wid] = incl;
    __syncthreads();
    int pre = 0, total = 0;
    #pragma unroll
    for (int w = 0; w < 4; ++w) {
        int tw = woff[w];
        if (w < wid) pre += tw;
        total += tw;
    }
    int base = pre + incl - cnt;
    if (mask) {
        int ib = chan * HW + ybase * WW + x0;
        #pragma unroll
        for (int j = 0; j < 8; ++j) {
            #pragma unroll
            for (int p = 0; p < 4; ++p) {
                if (mask & (1u << (j * 4 + p))) {
                    float v = (p == 0) ? L[j+1].x : (p == 1) ? L[j+1].y
                            : (p == 2) ? L[j+1].z : L[j+1].w;
                    if (base < BLK_SURV)
                        lsurv[base] = make_uint2(__float_as_uint(v),
                                                 (uint32_t)(ib + j * WW + p));
                    ++base;
                }
            }
        }
    }
    __syncthreads();

    // phase C: dense sigmoid + coalesced segment store (no hist)
    if (tid == 0) {
        blkcnt[bc * NSEG + seg] = min(total, BLK_SURV);
        if (total > BLK_SURV) ovf[bc] = 1;
    }
    int tt = min(total, BLK_SURV);
    uint64_t* sv = surv + ((size_t)bc * NSEG + seg) * BLK_SURV;
    for (int i = tid; i < tt; i += 256) {
        uint2 e = lsurv[i];
        uint32_t bt = __float_as_uint(sigmoidf(__uint_as_float(e.x)));
        sv[i] = ((uint64_t)bt << 32) | (uint32_t)(~e.y);
    }
}

// on-the-fly key for the (never-expected) survivor-overflow fallback
__device__ uint64_t key_at(const float* __restrict__ hb, int i) {
    float v = hb[i];
    int rem = i & (HW - 1);
    int y = rem >> 7, x = rem & (WW - 1);
    bool mx = true;
    if (y > 0) {
        if (x > 0      && hb[i - WW - 1] > v) mx = false;
        if (              hb[i - WW    ] > v) mx = false;
        if (x < WW - 1 && hb[i - WW + 1] > v) mx = false;
    }
    if (x > 0      && hb[i - 1] > v) mx = false;
    if (x < WW - 1 && hb[i + 1] > v) mx = false;
    if (y < HH - 1) {
        if (x > 0      && hb[i + WW - 1] > v) mx = false;
        if (              hb[i + WW    ] > v) mx = false;
        if (x < WW - 1 && hb[i + WW + 1] > v) mx = false;
    }
    if (!mx) return 0;
    return ((uint64_t)__float_as_uint(sigmoidf(v)) << 32) | (uint32_t)(~(uint32_t)i);
}

// ---- kernel 2: wide histogram over segmented survivor list ----
// u16-packed LDS bins (8 KB); per-block count <= 10240 so no u16 overflow.
__global__ void __launch_bounds__(256) k_hist(
        const uint64_t* __restrict__ surv, const int* __restrict__ blkcnt,
        const int* __restrict__ ovf,
        const float* __restrict__ tl, const float* __restrict__ br,
        const float* __restrict__ ct, uint32_t* __restrict__ hist) {
    __shared__ uint32_t lh2[NBINS / 2];
    for (int i = threadIdx.x; i < NBINS / 2; i += 256) lh2[i] = 0;
    __syncthreads();
    int bc = blockIdx.y;
    if (!ovf[bc]) {
        const uint64_t* sv = surv + (size_t)bc * NSEG * BLK_SURV;
        const int* bcnt = blkcnt + bc * NSEG;
        for (int i = blockIdx.x * 256 + threadIdx.x; i < NSEG * BLK_SURV;
             i += 16 * 256) {
            int seg = i >> 10, pos = i & (BLK_SURV - 1);
            if (pos < bcnt[seg]) {
                uint32_t bin = (uint32_t)(sv[i] >> 51);   // sigmoid bits >> 19
                atomicAdd(&lh2[bin >> 1], 1u << ((bin & 1) * 16));
            }
        }
    } else {
        int t = bc >> 3; int b = bc & 7;
        const float* heat = (t == 0) ? tl : (t == 1) ? br : ct;
        const float* hb = heat + (size_t)b * CHW;
        for (int i = blockIdx.x * 256 + threadIdx.x; i < CHW; i += 16 * 256) {
            uint64_t k = key_at(hb, i);
            if (k) {
                uint32_t bin = (uint32_t)(k >> 51);
                atomicAdd(&lh2[bin >> 1], 1u << ((bin & 1) * 16));
            }
        }
    }
    __syncthreads();
    uint32_t* gh = hist + (size_t)bc * NBINS;
    for (int i = threadIdx.x; i < NBINS / 2; i += 256) {
        uint32_t v = lh2[i];
        uint32_t lo = v & 0xFFFFu, hi = v >> 16;
        if (lo) atomicAdd(&gh[2 * i], lo);
        if (hi) atomicAdd(&gh[2 * i + 1], hi);
    }
}

// ---- kernel 3: parallel threshold find (24 blocks, 4096 bins) ----
__global__ void __launch_bounds__(256) k_thresh(const uint32_t* __restrict__ hist,
                                                int* __restrict__ thr) {
    __shared__ uint32_t csum[256];
    int bc = blockIdx.x;
    const uint32_t* h = hist + (size_t)bc * NBINS;
    int tid = threadIdx.x;
    uint32_t bins[16];
    #pragma unroll
    for (int i = 0; i < 16; ++i) bins[i] = h[tid * 16 + i];
    if (tid == 0) bins[0] = 0;  // bin 0 excluded
    uint32_t s = 0;
    #pragma unroll
    for (int i = 0; i < 16; ++i) s += bins[i];
    csum[tid] = s;
    __syncthreads();
    for (int step = 1; step < 256; step <<= 1) {
        uint32_t add = (tid + step < 256) ? csum[tid + step] : 0;
        __syncthreads();
        csum[tid] += add;
        __syncthreads();
    }
    uint32_t inc = csum[tid];
    uint32_t above = (tid + 1 < 256) ? csum[tid + 1] : 0;
    if (tid == 0 && inc < KTOP) thr[bc] = 1;
    if (above < KTOP && inc >= KTOP) {
        uint32_t cum = above;
        int T = 1;
        #pragma unroll
        for (int i = 15; i >= 0; --i) {
            cum += bins[i];
            if (cum >= KTOP) { T = tid * 16 + i; break; }
        }
        thr[bc] = T;
    }
}

// ---- kernel 4: wide filter of segmented survivors by bin >= T ----
__global__ void __launch_bounds__(256) k_filter(
        const uint64_t* __restrict__ surv, const int* __restrict__ blkcnt,
        const int* __restrict__ ovf, const int* __restrict__ thr,
        const float* __restrict__ tl, const float* __restrict__ br,
        const float* __restrict__ ct,
        uint64_t* __restrict__ cand, int* __restrict__ ccnt) {
    int bc = blockIdx.y;
    int T = thr[bc];
    if (!ovf[bc]) {
        const uint64_t* sv = surv + (size_t)bc * NSEG * BLK_SURV;
        const int* bcnt = blkcnt + bc * NSEG;
        for (int i = blockIdx.x * 256 + threadIdx.x; i < NSEG * BLK_SURV;
             i += 64 * 256) {
            int seg = i >> 10, pos = i & (BLK_SURV - 1);
            if (pos < bcnt[seg]) {
                uint64_t k = sv[i];
                if ((int)(uint32_t)(k >> 51) >= T) {
                    int pc = atomicAdd(&ccnt[bc * 32], 1);
                    if (pc < CAP) cand[(size_t)bc * CAP + pc] = k;
                }
            }
        }
    } else {
        int t = bc >> 3; int b = bc & 7;
        const float* heat = (t == 0) ? tl : (t == 1) ? br : ct;
        const float* hb = heat + (size_t)b * CHW;
        for (int i = blockIdx.x * 256 + threadIdx.x; i < CHW; i += 64 * 256) {
            uint64_t k = key_at(hb, i);
            if (k && (int)(uint32_t)(k >> 51) >= T) {
                int pc = atomicAdd(&ccnt[bc * 32], 1);
                if (pc < CAP) cand[(size_t)bc * CAP + pc] = k;
            }
        }
    }
}

// descending bitonic sort of N u64 keys in LDS
template <int N>
__device__ void bitonic_desc(uint64_t* k) {
    for (int kk = 2; kk <= N; kk <<= 1) {
        for (int j = kk >> 1; j > 0; j >>= 1) {
            __syncthreads();
            for (int i = threadIdx.x; i < N; i += blockDim.x) {
                int l = i ^ j;
                if (l > i) {
                    uint64_t a = k[i], b = k[l];
                    bool up = ((i & kk) == 0);
                    if (up ? (a < b) : (a > b)) { k[i] = b; k[l] = a; }
                }
            }
        }
    }
    __syncthreads();
}

// ---- kernel 5: per (tensor,batch) sort candidates, emit top-100 ----
__global__ void __launch_bounds__(1024) k_select(
        const uint64_t* __restrict__ cand, const int* __restrict__ ccnt,
        const float* __restrict__ tl_tag, const float* __restrict__ br_tag,
        const float* __restrict__ tl_regr, const float* __restrict__ br_regr,
        const float* __restrict__ ct_regr,
        float* __restrict__ cs, float* __restrict__ cx, float* __restrict__ cy,
        float* __restrict__ ce, int* __restrict__ ccls) {
    __shared__ uint64_t keys[CAP];
    int bc = blockIdx.x; int t = bc >> 3; int b = bc & 7;
    int n = ccnt[bc * 32]; if (n > CAP) n = CAP;
    if (n <= 512) {
        for (int i = threadIdx.x; i < 512; i += 1024)
            keys[i] = (i < n) ? cand[(size_t)bc * CAP + i] : 0ull;
        bitonic_desc<512>(keys);
    } else {
        for (int i = threadIdx.x; i < CAP; i += 1024)
            keys[i] = (i < n) ? cand[(size_t)bc * CAP + i] : 0ull;
        bitonic_desc<CAP>(keys);
    }
    if (threadIdx.x < KTOP) {
        uint64_t key = keys[threadIdx.x];
        float s = __uint_as_float((uint32_t)(key >> 32));
        uint32_t idx = ~(uint32_t)key;
        int cls = (int)(idx >> 14);
        int rem = (int)(idx & (HW - 1));
        int y = rem >> 7, x = rem & (WW - 1);
        const float* regr = (t == 0) ? tl_regr : (t == 1) ? br_regr : ct_regr;
        float o0 = regr[((size_t)b * 2 + 0) * HW + rem];
        float o1 = regr[((size_t)b * 2 + 1) * HW + rem];
        float emb = 0.f;
        if (t == 0) emb = tl_tag[(size_t)b * HW + rem];
        else if (t == 1) emb = br_tag[(size_t)b * HW + rem];
        int o = bc * KTOP + threadIdx.x;
        cs[o] = s;
        cx[o] = (float)x + o0;
        cy[o] = (float)y + o1;
        ce[o] = emb;
        ccls[o] = cls;
    }
}

// ---- kernel 6: fused pairwise scoring + final top-1000 + centers ----
__global__ void __launch_bounds__(1024) k_pairfinal(
        const float* __restrict__ cs, const float* __restrict__ cx,
        const float* __restrict__ cy, const float* __restrict__ ce,
        const int* __restrict__ ccls, float* __restrict__ out) {
    int b = blockIdx.x;
    __shared__ float ts[KTOP], tx[KTOP], ty[KTOP], te[KTOP];
    __shared__ int   tc[KTOP];
    __shared__ float bs_[KTOP], bx[KTOP], by[KTOP], be[KTOP];
    __shared__ int   bcl[KTOP];
    __shared__ uint64_t acc[ACAP];
    __shared__ int aidx[ACAP];
    __shared__ int acnt_s;
    int tid = threadIdx.x;
    if (tid == 0) acnt_s = 0;
    if (tid < KTOP) {
        int o = (0 * NB + b) * KTOP + tid;
        ts[tid] = cs[o]; tx[tid] = cx[o]; ty[tid] = cy[o]; te[tid] = ce[o]; tc[tid] = ccls[o];
    } else if (tid >= 512 && tid < 512 + KTOP) {
        int k = tid - 512;
        int o = (1 * NB + b) * KTOP + k;
        bs_[k] = cs[o]; bx[k] = cx[o]; by[k] = cy[o]; be[k] = ce[o]; bcl[k] = ccls[o];
    }
    __syncthreads();
    for (int p = tid; p < NPAIR; p += 1024) {
        int i = p / KTOP, j = p - i * KTOP;
        bool rej = (tc[i] != bcl[j])
                 | (fabsf(te[i] - be[j]) > 0.5f)
                 | (bx[j] < tx[i])
                 | (by[j] < ty[i]);
        if (!rej) {
            float sc = (ts[i] + bs_[j]) * 0.5f;
            int pos = atomicAdd(&acnt_s, 1);
            if (pos < ACAP)
                acc[pos] = ((uint64_t)__float_as_uint(sc) << 32) | (uint32_t)(~(uint32_t)p);
        }
    }
    __syncthreads();
    int m = acnt_s; if (m > ACAP) m = ACAP;
    if (m <= 256) {
        for (int i = tid; i < 256; i += 1024) if (i >= m) acc[i] = 0;
        bitonic_desc<256>(acc);
    } else {
        for (int i = tid; i < ACAP; i += 1024) if (i >= m) acc[i] = 0;
        bitonic_desc<ACAP>(acc);
    }
    for (int i = tid; i < m; i += 1024) aidx[i] = (int)(~(uint32_t)acc[i]);
    __syncthreads();
    for (int d = tid; d < NDET; d += 1024) {
        int p; float sc;
        if (d < m) {
            p = aidx[d];
            sc = __uint_as_float((uint32_t)(acc[d] >> 32));
        } else {
            // (d-m)-th flat pair-index NOT in accepted set, ascending (stable -1 ties)
            int r = d - m;
            int idx = r;
            for (;;) {
                int c = 0;
                for (int a = 0; a < m; ++a) c += (aidx[a] <= idx) ? 1 : 0;
                int ni = r + c;
                if (ni == idx) break;
                idx = ni;
            }
            p = idx; sc = -1.f;
        }
        int i = p / KTOP, j = p - i * KTOP;
        int ot = (0 * NB + b) * KTOP + i;
        int ob = (1 * NB + b) * KTOP + j;
        float* dr = out + ((size_t)b * NDET + d) * 8;
        dr[0] = cx[ot]; dr[1] = cy[ot]; dr[2] = cx[ob]; dr[3] = cy[ob];
        dr[4] = sc; dr[5] = cs[ot]; dr[6] = cs[ob]; dr[7] = (float)ccls[ot];
    }
    if (tid < KTOP) {
        int oc = (2 * NB + b) * KTOP + tid;
        float* cr = out + (size_t)NB * NDET * 8 + ((size_t)b * KTOP + tid) * 4;
        cr[0] = cx[oc]; cr[1] = cy[oc]; cr[2] = (float)ccls[oc]; cr[3] = cs[oc];
    }
}

extern "C" void kernel_launch(void* const* d_in, const int* in_sizes, int n_in,
                              void* d_out, int out_size, void* d_ws, size_t ws_size,
                              hipStream_t stream) {
    const float* tl_heat = (const float*)d_in[0];
    const float* br_heat = (const float*)d_in[1];
    const float* ct_heat = (const float*)d_in[2];
    const float* tl_tag  = (const float*)d_in[3];
    const float* br_tag  = (const float*)d_in[4];
    const float* tl_regr = (const float*)d_in[5];
    const float* br_regr = (const float*)d_in[6];
    const float* ct_regr = (const float*)d_in[7];

    if (ws_size < (size_t)WS_NEEDED) return;   // ~32.7 MB

    char* ws = (char*)d_ws;
    int*      ccnt   = (int*)(ws + OFF_CCNT);
    int*      ovf    = (int*)(ws + OFF_OVF);
    uint32_t* hist   = (uint32_t*)(ws + OFF_HIST);
    int*      thr    = (int*)(ws + OFF_THR);
    int*      blkcnt = (int*)(ws + OFF_BLKCNT);
    uint64_t* cand   = (uint64_t*)(ws + OFF_CAND);
    float*    cs     = (float*)(ws + OFF_CS);
    float*    cx     = (float*)(ws + OFF_CX);
    float*    cy     = (float*)(ws + OFF_CY);
    float*    ce     = (float*)(ws + OFF_CE);
    int*      ccls   = (int*)(ws + OFF_CCLS);
    uint64_t* surv   = (uint64_t*)(ws + OFF_SURV);

    hipMemsetAsync(ws, 0, ZERO_BYTES, stream);   // ccnt + ovf + hist

    k_nms<<<24 * NSEG, 256, 0, stream>>>(tl_heat, br_heat, ct_heat,
                                         surv, blkcnt, ovf);
    k_hist<<<dim3(16, 24), 256, 0, stream>>>(surv, blkcnt, ovf,
                                             tl_heat, br_heat, ct_heat, hist);
    k_thresh<<<24, 256, 0, stream>>>(hist, thr);
    k_filter<<<dim3(64, 24), 256, 0, stream>>>(surv, blkcnt, ovf, thr,
                                               tl_heat, br_heat, ct_heat,
                                               cand, ccnt);
    k_select<<<24, 1024, 0, stream>>>(cand, ccnt, tl_tag, br_tag,
                                      tl_regr, br_regr, ct_regr,
                                      cs, cx, cy, ce, ccls);
    k_pairfinal<<<NB, 1024, 0, stream>>>(cs, cx, cy, ce, ccls, (float*)d_out);
}

// Round 13
// 101.090 us; speedup vs baseline: 11.7449x; 1.4576x over previous
//
#include <hip/hip_runtime.h>
#include <cstdint>

// Problem constants (B=8, C=80, H=W=128, K=100, kernel=3, num_dets=1000)
#define NB    8
#define NC    80
#define HH    128
#define WW    128
#define HW    16384
#define CHW   1310720
#define KTOP  100
#define NDET  1000
#define NPAIR 10000
#define CAP   4096
#define ACAP  2048
#define NBINS 4096        // 12-bit bins over sigmoid bits (>>19) — proven resolution
#define BLK_SURV 1024     // per-block survivor segment (expect ~900)
#define NSEG  160         // k_nms blocks per (tensor,batch)

// ---- workspace layout (bytes) ----
#define OFF_CCNT   0                         // int[24*32] (one counter per 128B)
#define OFF_OVF    3072                      // int[32]
#define OFF_HIST   3200                      // u32[24][4096]
#define ZERO_BYTES 396416                    // ccnt+ovf+hist
#define OFF_THR    396416                    // int[32]
#define OFF_BLKCNT 396544                    // int[24*160]
#define OFF_CAND   411904                    // u64[24][4096]
#define OFF_CS     1198336                   // float[2400]
#define OFF_CX     1207936
#define OFF_CY     1217536
#define OFF_CE     1227136
#define OFF_CCLS   1236736                   // int[2400]
#define OFF_SURV   1246336                   // u64[24][160][1024] = 31.5 MB
#define WS_NEEDED  (OFF_SURV + 24*NSEG*BLK_SURV*8)

// branchless, bit-identical to jax.nn.sigmoid's two-branch form
__device__ __forceinline__ float sigmoidf(float x) {
    float e = expf(-fabsf(x));
    return (x >= 0.f ? 1.f : e) / (1.f + e);
}

// ---- kernel 1: NMS + compacted survivor segments (NO histogram work) ----
// (256,6): 85-VGPR budget so the 10 pinned row-loads stay in registers.
// (256,8) in R12 forced a 64-VGPR cap -> scratch spill -> 80MB/dir extra HBM.
__global__ void __launch_bounds__(256, 6) k_nms(
        const float* __restrict__ tl, const float* __restrict__ br,
        const float* __restrict__ ct,
        uint64_t* __restrict__ surv, int* __restrict__ blkcnt,
        int* __restrict__ ovf) {
    __shared__ uint2 lsurv[BLK_SURV];    // 8 KB
    __shared__ int   woff[4];

    int tid = threadIdx.x;
    int bid = blockIdx.x;
    int bc = bid / NSEG;                 // bc-major: co-resident blocks share L2
    int seg = bid - bc * NSEG;
    int t = bc >> 3; int b = bc & 7;
    const float* heat = (t == 0) ? tl : (t == 1) ? br : ct;
    int chan = seg >> 1;
    int half = seg & 1;
    const float* cb = heat + (size_t)b * CHW + (size_t)chan * HW;
    int lane = tid & 63;
    int wid = tid >> 6;
    int band = (wid << 1) + (lane >> 5);             // 0..7
    int ybase = half * 64 + band * 8;                // 0..120
    int x0 = (lane & 31) << 2;
    const float NEG = -__builtin_inff();

    // phase A: 10 unconditional loads (clamped row), pinned live
    float4 L[10];
    #pragma unroll
    for (int r = 0; r < 10; ++r) {
        int yy = ybase - 1 + r;
        int yc = min(max(yy, 0), HH - 1);
        L[r] = *(const float4*)(cb + yc * WW + x0);
    }
    #pragma unroll
    for (int r = 0; r < 10; ++r)
        asm volatile("" : "+v"(L[r].x), "+v"(L[r].y), "+v"(L[r].z), "+v"(L[r].w));
    if (ybase == 0)       L[0] = make_float4(NEG, NEG, NEG, NEG);
    if (ybase == HH - 8)  L[9] = make_float4(NEG, NEG, NEG, NEG);

    uint32_t mask = 0;
    #pragma unroll
    for (int j = 0; j < 8; ++j) {
        float c0 = fmaxf(fmaxf(L[j].x, L[j+1].x), L[j+2].x);
        float c1 = fmaxf(fmaxf(L[j].y, L[j+1].y), L[j+2].y);
        float c2 = fmaxf(fmaxf(L[j].z, L[j+1].z), L[j+2].z);
        float c3 = fmaxf(fmaxf(L[j].w, L[j+1].w), L[j+2].w);
        float cl = __shfl_up(c3, 1);
        float cr = __shfl_down(c0, 1);
        if (x0 == 0)      cl = NEG;
        if (x0 == WW - 4) cr = NEG;
        if (fmaxf(fmaxf(cl, c0), c1) == L[j+1].x) mask |= 1u << (j*4+0);
        if (fmaxf(fmaxf(c0, c1), c2) == L[j+1].y) mask |= 1u << (j*4+1);
        if (fmaxf(fmaxf(c1, c2), c3) == L[j+1].z) mask |= 1u << (j*4+2);
        if (fmaxf(fmaxf(c2, c3), cr) == L[j+1].w) mask |= 1u << (j*4+3);
    }

    // phase B: block-wide compaction into LDS (no global traffic)
    int cnt = __popc(mask);
    int incl = cnt;
    #pragma unroll
    for (int d = 1; d < 64; d <<= 1) {
        int u = __shfl_up(incl, d);
        if (lane >= d) incl += u;
    }
    if (lane == 63) woff[wid] = incl;
    __syncthreads();
    int pre = 0, total = 0;
    #pragma unroll
    for (int w = 0; w < 4; ++w) {
        int tw = woff[w];
        if (w < wid) pre += tw;
        total += tw;
    }
    int base = pre + incl - cnt;
    if (mask) {
        int ib = chan * HW + ybase * WW + x0;
        #pragma unroll
        for (int j = 0; j < 8; ++j) {
            #pragma unroll
            for (int p = 0; p < 4; ++p) {
                if (mask & (1u << (j * 4 + p))) {
                    float v = (p == 0) ? L[j+1].x : (p == 1) ? L[j+1].y
                            : (p == 2) ? L[j+1].z : L[j+1].w;
                    if (base < BLK_SURV)
                        lsurv[base] = make_uint2(__float_as_uint(v),
                                                 (uint32_t)(ib + j * WW + p));
                    ++base;
                }
            }
        }
    }
    __syncthreads();

    // phase C: dense sigmoid + coalesced segment store (no hist)
    if (tid == 0) {
        blkcnt[bc * NSEG + seg] = min(total, BLK_SURV);
        if (total > BLK_SURV) ovf[bc] = 1;
    }
    int tt = min(total, BLK_SURV);
    uint64_t* sv = surv + ((size_t)bc * NSEG + seg) * BLK_SURV;
    for (int i = tid; i < tt; i += 256) {
        uint2 e = lsurv[i];
        uint32_t bt = __float_as_uint(sigmoidf(__uint_as_float(e.x)));
        sv[i] = ((uint64_t)bt << 32) | (uint32_t)(~e.y);
    }
}

// on-the-fly key for the (never-expected) survivor-overflow fallback
__device__ uint64_t key_at(const float* __restrict__ hb, int i) {
    float v = hb[i];
    int rem = i & (HW - 1);
    int y = rem >> 7, x = rem & (WW - 1);
    bool mx = true;
    if (y > 0) {
        if (x > 0      && hb[i - WW - 1] > v) mx = false;
        if (              hb[i - WW    ] > v) mx = false;
        if (x < WW - 1 && hb[i - WW + 1] > v) mx = false;
    }
    if (x > 0      && hb[i - 1] > v) mx = false;
    if (x < WW - 1 && hb[i + 1] > v) mx = false;
    if (y < HH - 1) {
        if (x > 0      && hb[i + WW - 1] > v) mx = false;
        if (              hb[i + WW    ] > v) mx = false;
        if (x < WW - 1 && hb[i + WW + 1] > v) mx = false;
    }
    if (!mx) return 0;
    return ((uint64_t)__float_as_uint(sigmoidf(v)) << 32) | (uint32_t)(~(uint32_t)i);
}

// ---- kernel 2: wide histogram over segmented survivor list ----
__global__ void __launch_bounds__(256) k_hist(
        const uint64_t* __restrict__ surv, const int* __restrict__ blkcnt,
        const int* __restrict__ ovf,
        const float* __restrict__ tl, const float* __restrict__ br,
        const float* __restrict__ ct, uint32_t* __restrict__ hist) {
    __shared__ uint32_t lh2[NBINS / 2];
    for (int i = threadIdx.x; i < NBINS / 2; i += 256) lh2[i] = 0;
    __syncthreads();
    int bc = blockIdx.y;
    if (!ovf[bc]) {
        const uint64_t* sv = surv + (size_t)bc * NSEG * BLK_SURV;
        const int* bcnt = blkcnt + bc * NSEG;
        for (int i = blockIdx.x * 256 + threadIdx.x; i < NSEG * BLK_SURV;
             i += 16 * 256) {
            int seg = i >> 10, pos = i & (BLK_SURV - 1);
            if (pos < bcnt[seg]) {
                uint32_t bin = (uint32_t)(sv[i] >> 51);   // sigmoid bits >> 19
                atomicAdd(&lh2[bin >> 1], 1u << ((bin & 1) * 16));
            }
        }
    } else {
        int t = bc >> 3; int b = bc & 7;
        const float* heat = (t == 0) ? tl : (t == 1) ? br : ct;
        const float* hb = heat + (size_t)b * CHW;
        for (int i = blockIdx.x * 256 + threadIdx.x; i < CHW; i += 16 * 256) {
            uint64_t k = key_at(hb, i);
            if (k) {
                uint32_t bin = (uint32_t)(k >> 51);
                atomicAdd(&lh2[bin >> 1], 1u << ((bin & 1) * 16));
            }
        }
    }
    __syncthreads();
    uint32_t* gh = hist + (size_t)bc * NBINS;
    for (int i = threadIdx.x; i < NBINS / 2; i += 256) {
        uint32_t v = lh2[i];
        uint32_t lo = v & 0xFFFFu, hi = v >> 16;
        if (lo) atomicAdd(&gh[2 * i], lo);
        if (hi) atomicAdd(&gh[2 * i + 1], hi);
    }
}

// ---- kernel 3: parallel threshold find (24 blocks, 4096 bins) ----
__global__ void __launch_bounds__(256) k_thresh(const uint32_t* __restrict__ hist,
                                                int* __restrict__ thr) {
    __shared__ uint32_t csum[256];
    int bc = blockIdx.x;
    const uint32_t* h = hist + (size_t)bc * NBINS;
    int tid = threadIdx.x;
    uint32_t bins[16];
    #pragma unroll
    for (int i = 0; i < 16; ++i) bins[i] = h[tid * 16 + i];
    if (tid == 0) bins[0] = 0;  // bin 0 excluded
    uint32_t s = 0;
    #pragma unroll
    for (int i = 0; i < 16; ++i) s += bins[i];
    csum[tid] = s;
    __syncthreads();
    for (int step = 1; step < 256; step <<= 1) {
        uint32_t add = (tid + step < 256) ? csum[tid + step] : 0;
        __syncthreads();
        csum[tid] += add;
        __syncthreads();
    }
    uint32_t inc = csum[tid];
    uint32_t above = (tid + 1 < 256) ? csum[tid + 1] : 0;
    if (tid == 0 && inc < KTOP) thr[bc] = 1;
    if (above < KTOP && inc >= KTOP) {
        uint32_t cum = above;
        int T = 1;
        #pragma unroll
        for (int i = 15; i >= 0; --i) {
            cum += bins[i];
            if (cum >= KTOP) { T = tid * 16 + i; break; }
        }
        thr[bc] = T;
    }
}

// ---- kernel 4: wide filter of segmented survivors by bin >= T ----
__global__ void __launch_bounds__(256) k_filter(
        const uint64_t* __restrict__ surv, const int* __restrict__ blkcnt,
        const int* __restrict__ ovf, const int* __restrict__ thr,
        const float* __restrict__ tl, const float* __restrict__ br,
        const float* __restrict__ ct,
        uint64_t* __restrict__ cand, int* __restrict__ ccnt) {
    int bc = blockIdx.y;
    int T = thr[bc];
    if (!ovf[bc]) {
        const uint64_t* sv = surv + (size_t)bc * NSEG * BLK_SURV;
        const int* bcnt = blkcnt + bc * NSEG;
        for (int i = blockIdx.x * 256 + threadIdx.x; i < NSEG * BLK_SURV;
             i += 64 * 256) {
            int seg = i >> 10, pos = i & (BLK_SURV - 1);
            if (pos < bcnt[seg]) {
                uint64_t k = sv[i];
                if ((int)(uint32_t)(k >> 51) >= T) {
                    int pc = atomicAdd(&ccnt[bc * 32], 1);
                    if (pc < CAP) cand[(size_t)bc * CAP + pc] = k;
                }
            }
        }
    } else {
        int t = bc >> 3; int b = bc & 7;
        const float* heat = (t == 0) ? tl : (t == 1) ? br : ct;
        const float* hb = heat + (size_t)b * CHW;
        for (int i = blockIdx.x * 256 + threadIdx.x; i < CHW; i += 64 * 256) {
            uint64_t k = key_at(hb, i);
            if (k && (int)(uint32_t)(k >> 51) >= T) {
                int pc = atomicAdd(&ccnt[bc * 32], 1);
                if (pc < CAP) cand[(size_t)bc * CAP + pc] = k;
            }
        }
    }
}

// descending bitonic sort of N u64 keys in LDS
template <int N>
__device__ void bitonic_desc(uint64_t* k) {
    for (int kk = 2; kk <= N; kk <<= 1) {
        for (int j = kk >> 1; j > 0; j >>= 1) {
            __syncthreads();
            for (int i = threadIdx.x; i < N; i += blockDim.x) {
                int l = i ^ j;
                if (l > i) {
                    uint64_t a = k[i], b = k[l];
                    bool up = ((i & kk) == 0);
                    if (up ? (a < b) : (a > b)) { k[i] = b; k[l] = a; }
                }
            }
        }
    }
    __syncthreads();
}

// ---- kernel 5: per (tensor,batch) sort candidates, emit top-100 ----
__global__ void __launch_bounds__(1024) k_select(
        const uint64_t* __restrict__ cand, const int* __restrict__ ccnt,
        const float* __restrict__ tl_tag, const float* __restrict__ br_tag,
        const float* __restrict__ tl_regr, const float* __restrict__ br_regr,
        const float* __restrict__ ct_regr,
        float* __restrict__ cs, float* __restrict__ cx, float* __restrict__ cy,
        float* __restrict__ ce, int* __restrict__ ccls) {
    __shared__ uint64_t keys[CAP];
    int bc = blockIdx.x; int t = bc >> 3; int b = bc & 7;
    int n = ccnt[bc * 32]; if (n > CAP) n = CAP;
    if (n <= 512) {
        for (int i = threadIdx.x; i < 512; i += 1024)
            keys[i] = (i < n) ? cand[(size_t)bc * CAP + i] : 0ull;
        bitonic_desc<512>(keys);
    } else {
        for (int i = threadIdx.x; i < CAP; i += 1024)
            keys[i] = (i < n) ? cand[(size_t)bc * CAP + i] : 0ull;
        bitonic_desc<CAP>(keys);
    }
    if (threadIdx.x < KTOP) {
        uint64_t key = keys[threadIdx.x];
        float s = __uint_as_float((uint32_t)(key >> 32));
        uint32_t idx = ~(uint32_t)key;
        int cls = (int)(idx >> 14);
        int rem = (int)(idx & (HW - 1));
        int y = rem >> 7, x = rem & (WW - 1);
        const float* regr = (t == 0) ? tl_regr : (t == 1) ? br_regr : ct_regr;
        float o0 = regr[((size_t)b * 2 + 0) * HW + rem];
        float o1 = regr[((size_t)b * 2 + 1) * HW + rem];
        float emb = 0.f;
        if (t == 0) emb = tl_tag[(size_t)b * HW + rem];
        else if (t == 1) emb = br_tag[(size_t)b * HW + rem];
        int o = bc * KTOP + threadIdx.x;
        cs[o] = s;
        cx[o] = (float)x + o0;
        cy[o] = (float)y + o1;
        ce[o] = emb;
        ccls[o] = cls;
    }
}

// ---- kernel 6: fused pairwise scoring + final top-1000 + centers ----
__global__ void __launch_bounds__(1024) k_pairfinal(
        const float* __restrict__ cs, const float* __restrict__ cx,
        const float* __restrict__ cy, const float* __restrict__ ce,
        const int* __restrict__ ccls, float* __restrict__ out) {
    int b = blockIdx.x;
    __shared__ float ts[KTOP], tx[KTOP], ty[KTOP], te[KTOP];
    __shared__ int   tc[KTOP];
    __shared__ float bs_[KTOP], bx[KTOP], by[KTOP], be[KTOP];
    __shared__ int   bcl[KTOP];
    __shared__ uint64_t acc[ACAP];
    __shared__ int aidx[ACAP];
    __shared__ int acnt_s;
    int tid = threadIdx.x;
    if (tid == 0) acnt_s = 0;
    if (tid < KTOP) {
        int o = (0 * NB + b) * KTOP + tid;
        ts[tid] = cs[o]; tx[tid] = cx[o]; ty[tid] = cy[o]; te[tid] = ce[o]; tc[tid] = ccls[o];
    } else if (tid >= 512 && tid < 512 + KTOP) {
        int k = tid - 512;
        int o = (1 * NB + b) * KTOP + k;
        bs_[k] = cs[o]; bx[k] = cx[o]; by[k] = cy[o]; be[k] = ce[o]; bcl[k] = ccls[o];
    }
    __syncthreads();
    for (int p = tid; p < NPAIR; p += 1024) {
        int i = p / KTOP, j = p - i * KTOP;
        bool rej = (tc[i] != bcl[j])
                 | (fabsf(te[i] - be[j]) > 0.5f)
                 | (bx[j] < tx[i])
                 | (by[j] < ty[i]);
        if (!rej) {
            float sc = (ts[i] + bs_[j]) * 0.5f;
            int pos = atomicAdd(&acnt_s, 1);
            if (pos < ACAP)
                acc[pos] = ((uint64_t)__float_as_uint(sc) << 32) | (uint32_t)(~(uint32_t)p);
        }
    }
    __syncthreads();
    int m = acnt_s; if (m > ACAP) m = ACAP;
    if (m <= 256) {
        for (int i = tid; i < 256; i += 1024) if (i >= m) acc[i] = 0;
        bitonic_desc<256>(acc);
    } else {
        for (int i = tid; i < ACAP; i += 1024) if (i >= m) acc[i] = 0;
        bitonic_desc<ACAP>(acc);
    }
    for (int i = tid; i < m; i += 1024) aidx[i] = (int)(~(uint32_t)acc[i]);
    __syncthreads();
    for (int d = tid; d < NDET; d += 1024) {
        int p; float sc;
        if (d < m) {
            p = aidx[d];
            sc = __uint_as_float((uint32_t)(acc[d] >> 32));
        } else {
            // (d-m)-th flat pair-index NOT in accepted set, ascending (stable -1 ties)
            int r = d - m;
            int idx = r;
            for (;;) {
                int c = 0;
                for (int a = 0; a < m; ++a) c += (aidx[a] <= idx) ? 1 : 0;
                int ni = r + c;
                if (ni == idx) break;
                idx = ni;
            }
            p = idx; sc = -1.f;
        }
        int i = p / KTOP, j = p - i * KTOP;
        int ot = (0 * NB + b) * KTOP + i;
        int ob = (1 * NB + b) * KTOP + j;
        float* dr = out + ((size_t)b * NDET + d) * 8;
        dr[0] = cx[ot]; dr[1] = cy[ot]; dr[2] = cx[ob]; dr[3] = cy[ob];
        dr[4] = sc; dr[5] = cs[ot]; dr[6] = cs[ob]; dr[7] = (float)ccls[ot];
    }
    if (tid < KTOP) {
        int oc = (2 * NB + b) * KTOP + tid;
        float* cr = out + (size_t)NB * NDET * 8 + ((size_t)b * KTOP + tid) * 4;
        cr[0] = cx[oc]; cr[1] = cy[oc]; cr[2] = (float)ccls[oc]; cr[3] = cs[oc];
    }
}

extern "C" void kernel_launch(void* const* d_in, const int* in_sizes, int n_in,
                              void* d_out, int out_size, void* d_ws, size_t ws_size,
                              hipStream_t stream) {
    const float* tl_heat = (const float*)d_in[0];
    const float* br_heat = (const float*)d_in[1];
    const float* ct_heat = (const float*)d_in[2];
    const float* tl_tag  = (const float*)d_in[3];
    const float* br_tag  = (const float*)d_in[4];
    const float* tl_regr = (const float*)d_in[5];
    const float* br_regr = (const float*)d_in[6];
    const float* ct_regr = (const float*)d_in[7];

    if (ws_size < (size_t)WS_NEEDED) return;   // ~32.7 MB

    char* ws = (char*)d_ws;
    int*      ccnt   = (int*)(ws + OFF_CCNT);
    int*      ovf    = (int*)(ws + OFF_OVF);
    uint32_t* hist   = (uint32_t*)(ws + OFF_HIST);
    int*      thr    = (int*)(ws + OFF_THR);
    int*      blkcnt = (int*)(ws + OFF_BLKCNT);
    uint64_t* cand   = (uint64_t*)(ws + OFF_CAND);
    float*    cs     = (float*)(ws + OFF_CS);
    float*    cx     = (float*)(ws + OFF_CX);
    float*    cy     = (float*)(ws + OFF_CY);
    float*    ce     = (float*)(ws + OFF_CE);
    int*      ccls   = (int*)(ws + OFF_CCLS);
    uint64_t* surv   = (uint64_t*)(ws + OFF_SURV);

    hipMemsetAsync(ws, 0, ZERO_BYTES, stream);   // ccnt + ovf + hist

    k_nms<<<24 * NSEG, 256, 0, stream>>>(tl_heat, br_heat, ct_heat,
                                         surv, blkcnt, ovf);
    k_hist<<<dim3(16, 24), 256, 0, stream>>>(surv, blkcnt, ovf,
                                             tl_heat, br_heat, ct_heat, hist);
    k_thresh<<<24, 256, 0, stream>>>(hist, thr);
    k_filter<<<dim3(64, 24), 256, 0, stream>>>(surv, blkcnt, ovf, thr,
                                               tl_heat, br_heat, ct_heat,
                                               cand, ccnt);
    k_select<<<24, 1024, 0, stream>>>(cand, ccnt, tl_tag, br_tag,
                                      tl_regr, br_regr, ct_regr,
                                      cs, cx, cy, ce, ccls);
    k_pairfinal<<<NB, 1024, 0, stream>>>(cs, cx, cy, ce, ccls, (float*)d_out);
}

// Round 14
// 78.030 us; speedup vs baseline: 15.2159x; 1.2955x over previous
//
#include <hip/hip_runtime.h>
#include <cstdint>

// Problem constants (B=8, C=80, H=W=128, K=100, kernel=3, num_dets=1000)
#define NB    8
#define NC    80
#define HH    128
#define WW    128
#define HW    16384
#define CHW   1310720
#define KTOP  100
#define NDET  1000
#define NPAIR 10000
#define CAP   4096
#define ACAP  2048
#define NBINS 4096        // 12-bit bins over sigmoid bits (>>19) — proven resolution
#define BLK_SURV 1024     // per-block survivor segment (expect ~900)
#define NSEG  160         // k_nms blocks per (tensor,batch)

// ---- workspace layout (bytes) ----
#define OFF_CCNT   0                         // int[24*32] (one counter per 128B)
#define OFF_OVF    3072                      // int[32]
#define OFF_HIST   3200                      // u32[24][4096]
#define ZERO_BYTES 396416                    // ccnt+ovf+hist
#define OFF_BLKCNT 396544                    // int[24*160]
#define OFF_CAND   411904                    // u64[24][4096]
#define OFF_CS     1198336                   // float[2400]
#define OFF_CX     1207936
#define OFF_CY     1217536
#define OFF_CE     1227136
#define OFF_CCLS   1236736                   // int[2400]
#define OFF_SURV   1246336                   // u64[24][160][1024] = 31.5 MB
#define WS_NEEDED  (OFF_SURV + 24*NSEG*BLK_SURV*8)

// branchless, bit-identical to jax.nn.sigmoid's two-branch form
__device__ __forceinline__ float sigmoidf(float x) {
    float e = expf(-fabsf(x));
    return (x >= 0.f ? 1.f : e) / (1.f + e);
}

// ---- kernel 1: NMS + compacted survivor segments + fused u16 LDS hist ----
// (256,7): 28 waves/CU (R9 was 6 -> 24); VGPR cap ~73 >> ~40 needed, no spill.
// Hist stays fused: standalone hist kernel measured +26us (R13); fused costs ~4us.
__global__ void __launch_bounds__(256, 7) k_nms(
        const float* __restrict__ tl, const float* __restrict__ br,
        const float* __restrict__ ct,
        uint64_t* __restrict__ surv, int* __restrict__ blkcnt,
        int* __restrict__ ovf, uint32_t* __restrict__ hist) {
    __shared__ uint32_t lh2[NBINS / 2];     // u16-packed bins, 8 KB
    __shared__ uint2    lsurv[BLK_SURV];    // 8 KB
    __shared__ int      woff[4];

    int tid = threadIdx.x;
    for (int i = tid; i < NBINS / 2; i += 256) lh2[i] = 0;

    int bid = blockIdx.x;
    int bc = bid / NSEG;                 // bc-major: co-resident blocks share L2
    int seg = bid - bc * NSEG;
    int t = bc >> 3; int b = bc & 7;
    const float* heat = (t == 0) ? tl : (t == 1) ? br : ct;
    int chan = seg >> 1;
    int half = seg & 1;
    const float* cb = heat + (size_t)b * CHW + (size_t)chan * HW;
    int lane = tid & 63;
    int wid = tid >> 6;
    int band = (wid << 1) + (lane >> 5);             // 0..7
    int ybase = half * 64 + band * 8;                // 0..120
    int x0 = (lane & 31) << 2;
    const float NEG = -__builtin_inff();

    // phase A: 10 unconditional loads (clamped row), pinned live
    float4 L[10];
    #pragma unroll
    for (int r = 0; r < 10; ++r) {
        int yy = ybase - 1 + r;
        int yc = min(max(yy, 0), HH - 1);
        L[r] = *(const float4*)(cb + yc * WW + x0);
    }
    #pragma unroll
    for (int r = 0; r < 10; ++r)
        asm volatile("" : "+v"(L[r].x), "+v"(L[r].y), "+v"(L[r].z), "+v"(L[r].w));
    if (ybase == 0)       L[0] = make_float4(NEG, NEG, NEG, NEG);
    if (ybase == HH - 8)  L[9] = make_float4(NEG, NEG, NEG, NEG);

    uint32_t mask = 0;
    #pragma unroll
    for (int j = 0; j < 8; ++j) {
        float c0 = fmaxf(fmaxf(L[j].x, L[j+1].x), L[j+2].x);
        float c1 = fmaxf(fmaxf(L[j].y, L[j+1].y), L[j+2].y);
        float c2 = fmaxf(fmaxf(L[j].z, L[j+1].z), L[j+2].z);
        float c3 = fmaxf(fmaxf(L[j].w, L[j+1].w), L[j+2].w);
        float cl = __shfl_up(c3, 1);
        float cr = __shfl_down(c0, 1);
        if (x0 == 0)      cl = NEG;
        if (x0 == WW - 4) cr = NEG;
        if (fmaxf(fmaxf(cl, c0), c1) == L[j+1].x) mask |= 1u << (j*4+0);
        if (fmaxf(fmaxf(c0, c1), c2) == L[j+1].y) mask |= 1u << (j*4+1);
        if (fmaxf(fmaxf(c1, c2), c3) == L[j+1].z) mask |= 1u << (j*4+2);
        if (fmaxf(fmaxf(c2, c3), cr) == L[j+1].w) mask |= 1u << (j*4+3);
    }

    // phase B: block-wide compaction into LDS (no global traffic)
    int cnt = __popc(mask);
    int incl = cnt;
    #pragma unroll
    for (int d = 1; d < 64; d <<= 1) {
        int u = __shfl_up(incl, d);
        if (lane >= d) incl += u;
    }
    if (lane == 63) woff[wid] = incl;
    __syncthreads();
    int pre = 0, total = 0;
    #pragma unroll
    for (int w = 0; w < 4; ++w) {
        int tw = woff[w];
        if (w < wid) pre += tw;
        total += tw;
    }
    int base = pre + incl - cnt;
    if (mask) {
        int ib = chan * HW + ybase * WW + x0;
        #pragma unroll
        for (int j = 0; j < 8; ++j) {
            #pragma unroll
            for (int p = 0; p < 4; ++p) {
                if (mask & (1u << (j * 4 + p))) {
                    float v = (p == 0) ? L[j+1].x : (p == 1) ? L[j+1].y
                            : (p == 2) ? L[j+1].z : L[j+1].w;
                    if (base < BLK_SURV)
                        lsurv[base] = make_uint2(__float_as_uint(v),
                                                 (uint32_t)(ib + j * WW + p));
                    ++base;
                }
            }
        }
    }
    __syncthreads();

    // phase C: dense sigmoid + u16 hist + coalesced segment store
    if (tid == 0) {
        blkcnt[bc * NSEG + seg] = min(total, BLK_SURV);
        if (total > BLK_SURV) ovf[bc] = 1;
    }
    int tt = min(total, BLK_SURV);
    uint64_t* sv = surv + ((size_t)bc * NSEG + seg) * BLK_SURV;
    for (int i = tid; i < tt; i += 256) {
        uint2 e = lsurv[i];
        uint32_t bt = __float_as_uint(sigmoidf(__uint_as_float(e.x)));
        uint32_t bin = bt >> 19;
        atomicAdd(&lh2[bin >> 1], 1u << ((bin & 1) * 16));
        sv[i] = ((uint64_t)bt << 32) | (uint32_t)(~e.y);
    }
    __syncthreads();
    // merge: <=1 global atomic per (block,bin) -> bounded contention (R10 lesson)
    uint32_t* gh = hist + (size_t)bc * NBINS;
    for (int i = tid; i < NBINS / 2; i += 256) {
        uint32_t v = lh2[i];
        uint32_t lo = v & 0xFFFFu, hi = v >> 16;
        if (lo) atomicAdd(&gh[2 * i], lo);
        if (hi) atomicAdd(&gh[2 * i + 1], hi);
    }
}

// on-the-fly key for the (never-expected) survivor-overflow fallback
__device__ uint64_t key_at(const float* __restrict__ hb, int i) {
    float v = hb[i];
    int rem = i & (HW - 1);
    int y = rem >> 7, x = rem & (WW - 1);
    bool mx = true;
    if (y > 0) {
        if (x > 0      && hb[i - WW - 1] > v) mx = false;
        if (              hb[i - WW    ] > v) mx = false;
        if (x < WW - 1 && hb[i - WW + 1] > v) mx = false;
    }
    if (x > 0      && hb[i - 1] > v) mx = false;
    if (x < WW - 1 && hb[i + 1] > v) mx = false;
    if (y < HH - 1) {
        if (x > 0      && hb[i + WW - 1] > v) mx = false;
        if (              hb[i + WW    ] > v) mx = false;
        if (x < WW - 1 && hb[i + WW + 1] > v) mx = false;
    }
    if (!mx) return 0;
    return ((uint64_t)__float_as_uint(sigmoidf(v)) << 32) | (uint32_t)(~(uint32_t)i);
}

// ---- kernel 2: fused threshold + wide filter of segmented survivors ----
// Each block recomputes T from the histogram (deterministic, ~16KB L2 read),
// removing the separate k_thresh dispatch.
__global__ void __launch_bounds__(256) k_filter(
        const uint32_t* __restrict__ hist,
        const uint64_t* __restrict__ surv, const int* __restrict__ blkcnt,
        const int* __restrict__ ovf,
        const float* __restrict__ tl, const float* __restrict__ br,
        const float* __restrict__ ct,
        uint64_t* __restrict__ cand, int* __restrict__ ccnt) {
    __shared__ uint32_t csum[256];
    __shared__ int thr_s;
    int bc = blockIdx.y;
    int tid = threadIdx.x;

    // threshold: suffix-scan over 4096 bins, 16 bins/thread (k_thresh semantics)
    const uint32_t* h = hist + (size_t)bc * NBINS;
    uint32_t bins[16];
    #pragma unroll
    for (int i = 0; i < 16; ++i) bins[i] = h[tid * 16 + i];
    if (tid == 0) bins[0] = 0;  // bin 0 excluded
    uint32_t s = 0;
    #pragma unroll
    for (int i = 0; i < 16; ++i) s += bins[i];
    csum[tid] = s;
    __syncthreads();
    for (int step = 1; step < 256; step <<= 1) {
        uint32_t add = (tid + step < 256) ? csum[tid + step] : 0;
        __syncthreads();
        csum[tid] += add;
        __syncthreads();
    }
    uint32_t inc = csum[tid];
    uint32_t above = (tid + 1 < 256) ? csum[tid + 1] : 0;
    if (tid == 0 && inc < KTOP) thr_s = 1;
    if (above < KTOP && inc >= KTOP) {
        uint32_t cum = above;
        int T = 1;
        #pragma unroll
        for (int i = 15; i >= 0; --i) {
            cum += bins[i];
            if (cum >= KTOP) { T = tid * 16 + i; break; }
        }
        thr_s = T;
    }
    __syncthreads();
    int T = thr_s;

    if (!ovf[bc]) {
        const uint64_t* sv = surv + (size_t)bc * NSEG * BLK_SURV;
        const int* bcnt = blkcnt + bc * NSEG;
        for (int i = blockIdx.x * 256 + threadIdx.x; i < NSEG * BLK_SURV;
             i += 64 * 256) {
            int seg = i >> 10, pos = i & (BLK_SURV - 1);
            if (pos < bcnt[seg]) {
                uint64_t k = sv[i];
                if ((int)(uint32_t)(k >> 51) >= T) {
                    int pc = atomicAdd(&ccnt[bc * 32], 1);
                    if (pc < CAP) cand[(size_t)bc * CAP + pc] = k;
                }
            }
        }
    } else {
        int t = bc >> 3; int b = bc & 7;
        const float* heat = (t == 0) ? tl : (t == 1) ? br : ct;
        const float* hb = heat + (size_t)b * CHW;
        for (int i = blockIdx.x * 256 + threadIdx.x; i < CHW; i += 64 * 256) {
            uint64_t k = key_at(hb, i);
            if (k && (int)(uint32_t)(k >> 51) >= T) {
                int pc = atomicAdd(&ccnt[bc * 32], 1);
                if (pc < CAP) cand[(size_t)bc * CAP + pc] = k;
            }
        }
    }
}

// descending bitonic sort of N u64 keys in LDS
template <int N>
__device__ void bitonic_desc(uint64_t* k) {
    for (int kk = 2; kk <= N; kk <<= 1) {
        for (int j = kk >> 1; j > 0; j >>= 1) {
            __syncthreads();
            for (int i = threadIdx.x; i < N; i += blockDim.x) {
                int l = i ^ j;
                if (l > i) {
                    uint64_t a = k[i], b = k[l];
                    bool up = ((i & kk) == 0);
                    if (up ? (a < b) : (a > b)) { k[i] = b; k[l] = a; }
                }
            }
        }
    }
    __syncthreads();
}

// ---- kernel 3: per (tensor,batch) sort candidates, emit top-100 ----
__global__ void __launch_bounds__(1024) k_select(
        const uint64_t* __restrict__ cand, const int* __restrict__ ccnt,
        const float* __restrict__ tl_tag, const float* __restrict__ br_tag,
        const float* __restrict__ tl_regr, const float* __restrict__ br_regr,
        const float* __restrict__ ct_regr,
        float* __restrict__ cs, float* __restrict__ cx, float* __restrict__ cy,
        float* __restrict__ ce, int* __restrict__ ccls) {
    __shared__ uint64_t keys[CAP];
    int bc = blockIdx.x; int t = bc >> 3; int b = bc & 7;
    int n = ccnt[bc * 32]; if (n > CAP) n = CAP;
    if (n <= 512) {
        for (int i = threadIdx.x; i < 512; i += 1024)
            keys[i] = (i < n) ? cand[(size_t)bc * CAP + i] : 0ull;
        bitonic_desc<512>(keys);
    } else {
        for (int i = threadIdx.x; i < CAP; i += 1024)
            keys[i] = (i < n) ? cand[(size_t)bc * CAP + i] : 0ull;
        bitonic_desc<CAP>(keys);
    }
    if (threadIdx.x < KTOP) {
        uint64_t key = keys[threadIdx.x];
        float s = __uint_as_float((uint32_t)(key >> 32));
        uint32_t idx = ~(uint32_t)key;
        int cls = (int)(idx >> 14);
        int rem = (int)(idx & (HW - 1));
        int y = rem >> 7, x = rem & (WW - 1);
        const float* regr = (t == 0) ? tl_regr : (t == 1) ? br_regr : ct_regr;
        float o0 = regr[((size_t)b * 2 + 0) * HW + rem];
        float o1 = regr[((size_t)b * 2 + 1) * HW + rem];
        float emb = 0.f;
        if (t == 0) emb = tl_tag[(size_t)b * HW + rem];
        else if (t == 1) emb = br_tag[(size_t)b * HW + rem];
        int o = bc * KTOP + threadIdx.x;
        cs[o] = s;
        cx[o] = (float)x + o0;
        cy[o] = (float)y + o1;
        ce[o] = emb;
        ccls[o] = cls;
    }
}

// ---- kernel 4: fused pairwise scoring + final top-1000 + centers ----
__global__ void __launch_bounds__(1024) k_pairfinal(
        const float* __restrict__ cs, const float* __restrict__ cx,
        const float* __restrict__ cy, const float* __restrict__ ce,
        const int* __restrict__ ccls, float* __restrict__ out) {
    int b = blockIdx.x;
    __shared__ float ts[KTOP], tx[KTOP], ty[KTOP], te[KTOP];
    __shared__ int   tc[KTOP];
    __shared__ float bs_[KTOP], bx[KTOP], by[KTOP], be[KTOP];
    __shared__ int   bcl[KTOP];
    __shared__ uint64_t acc[ACAP];
    __shared__ int aidx[ACAP];
    __shared__ int acnt_s;
    int tid = threadIdx.x;
    if (tid == 0) acnt_s = 0;
    if (tid < KTOP) {
        int o = (0 * NB + b) * KTOP + tid;
        ts[tid] = cs[o]; tx[tid] = cx[o]; ty[tid] = cy[o]; te[tid] = ce[o]; tc[tid] = ccls[o];
    } else if (tid >= 512 && tid < 512 + KTOP) {
        int k = tid - 512;
        int o = (1 * NB + b) * KTOP + k;
        bs_[k] = cs[o]; bx[k] = cx[o]; by[k] = cy[o]; be[k] = ce[o]; bcl[k] = ccls[o];
    }
    __syncthreads();
    for (int p = tid; p < NPAIR; p += 1024) {
        int i = p / KTOP, j = p - i * KTOP;
        bool rej = (tc[i] != bcl[j])
                 | (fabsf(te[i] - be[j]) > 0.5f)
                 | (bx[j] < tx[i])
                 | (by[j] < ty[i]);
        if (!rej) {
            float sc = (ts[i] + bs_[j]) * 0.5f;
            int pos = atomicAdd(&acnt_s, 1);
            if (pos < ACAP)
                acc[pos] = ((uint64_t)__float_as_uint(sc) << 32) | (uint32_t)(~(uint32_t)p);
        }
    }
    __syncthreads();
    int m = acnt_s; if (m > ACAP) m = ACAP;
    if (m <= 256) {
        for (int i = tid; i < 256; i += 1024) if (i >= m) acc[i] = 0;
        bitonic_desc<256>(acc);
    } else {
        for (int i = tid; i < ACAP; i += 1024) if (i >= m) acc[i] = 0;
        bitonic_desc<ACAP>(acc);
    }
    for (int i = tid; i < m; i += 1024) aidx[i] = (int)(~(uint32_t)acc[i]);
    __syncthreads();
    for (int d = tid; d < NDET; d += 1024) {
        int p; float sc;
        if (d < m) {
            p = aidx[d];
            sc = __uint_as_float((uint32_t)(acc[d] >> 32));
        } else {
            // (d-m)-th flat pair-index NOT in accepted set, ascending (stable -1 ties)
            int r = d - m;
            int idx = r;
            for (;;) {
                int c = 0;
                for (int a = 0; a < m; ++a) c += (aidx[a] <= idx) ? 1 : 0;
                int ni = r + c;
                if (ni == idx) break;
                idx = ni;
            }
            p = idx; sc = -1.f;
        }
        int i = p / KTOP, j = p - i * KTOP;
        int ot = (0 * NB + b) * KTOP + i;
        int ob = (1 * NB + b) * KTOP + j;
        float* dr = out + ((size_t)b * NDET + d) * 8;
        dr[0] = cx[ot]; dr[1] = cy[ot]; dr[2] = cx[ob]; dr[3] = cy[ob];
        dr[4] = sc; dr[5] = cs[ot]; dr[6] = cs[ob]; dr[7] = (float)ccls[ot];
    }
    if (tid < KTOP) {
        int oc = (2 * NB + b) * KTOP + tid;
        float* cr = out + (size_t)NB * NDET * 8 + ((size_t)b * KTOP + tid) * 4;
        cr[0] = cx[oc]; cr[1] = cy[oc]; cr[2] = (float)ccls[oc]; cr[3] = cs[oc];
    }
}

extern "C" void kernel_launch(void* const* d_in, const int* in_sizes, int n_in,
                              void* d_out, int out_size, void* d_ws, size_t ws_size,
                              hipStream_t stream) {
    const float* tl_heat = (const float*)d_in[0];
    const float* br_heat = (const float*)d_in[1];
    const float* ct_heat = (const float*)d_in[2];
    const float* tl_tag  = (const float*)d_in[3];
    const float* br_tag  = (const float*)d_in[4];
    const float* tl_regr = (const float*)d_in[5];
    const float* br_regr = (const float*)d_in[6];
    const float* ct_regr = (const float*)d_in[7];

    if (ws_size < (size_t)WS_NEEDED) return;   // ~32.7 MB

    char* ws = (char*)d_ws;
    int*      ccnt   = (int*)(ws + OFF_CCNT);
    int*      ovf    = (int*)(ws + OFF_OVF);
    uint32_t* hist   = (uint32_t*)(ws + OFF_HIST);
    int*      blkcnt = (int*)(ws + OFF_BLKCNT);
    uint64_t* cand   = (uint64_t*)(ws + OFF_CAND);
    float*    cs     = (float*)(ws + OFF_CS);
    float*    cx     = (float*)(ws + OFF_CX);
    float*    cy     = (float*)(ws + OFF_CY);
    float*    ce     = (float*)(ws + OFF_CE);
    int*      ccls   = (int*)(ws + OFF_CCLS);
    uint64_t* surv   = (uint64_t*)(ws + OFF_SURV);

    hipMemsetAsync(ws, 0, ZERO_BYTES, stream);   // ccnt + ovf + hist

    k_nms<<<24 * NSEG, 256, 0, stream>>>(tl_heat, br_heat, ct_heat,
                                         surv, blkcnt, ovf, hist);
    k_filter<<<dim3(64, 24), 256, 0, stream>>>(hist, surv, blkcnt, ovf,
                                               tl_heat, br_heat, ct_heat,
                                               cand, ccnt);
    k_select<<<24, 1024, 0, stream>>>(cand, ccnt, tl_tag, br_tag,
                                      tl_regr, br_regr, ct_regr,
                                      cs, cx, cy, ce, ccls);
    k_pairfinal<<<NB, 1024, 0, stream>>>(cs, cx, cy, ce, ccls, (float*)d_out);
}